// Round 15
// baseline (266.422 us; speedup 1.0000x reference)
//
#include <hip/hip_runtime.h>

// DefectNet forward. Round 15 = round 14 (233.1us) +
//  - knn pass-B chunk reorder {3,0,1,2}: LDS still holds ch3 from pass A,
//    skip one 32KB re-stage + 2 barriers (collect order is irrelevant)
//  - attn logits via v_dot2_f32_f16 (guarded; h2f fallback)
//  - colsum 128 blocks (gpart 128x512 in ex-attw slot)

#define NP 8192
#define NDOWN 2048
#define KCAP 32

typedef unsigned long long u64;
typedef __attribute__((ext_vector_type(8))) _Float16 half8;
typedef __attribute__((ext_vector_type(2))) _Float16 h2v;
typedef __attribute__((ext_vector_type(4))) unsigned short us4;
typedef __attribute__((ext_vector_type(8))) unsigned short ushort8;
typedef __attribute__((ext_vector_type(4))) float f32x4;

__device__ __forceinline__ bool lexless(float ad, int ai, float bd, int bi) {
  return ad < bd || (ad == bd && ai < bi);
}

__device__ __forceinline__ unsigned short f2h(float x) {
  _Float16 h = (_Float16)x;
  return __builtin_bit_cast(unsigned short, h);
}
__device__ __forceinline__ float h2f(unsigned short u) {
  return (float)__builtin_bit_cast(_Float16, u);
}

// ---------------- prep (points + weight transpose, merged) ----------------
__global__ __launch_bounds__(256) void prep_all_k(
    const float* __restrict__ pts, float4* __restrict__ soa,
    const float* __restrict__ We2, const float* __restrict__ Wq1,
    const float* __restrict__ Wk1, const float* __restrict__ Wv1,
    const float* __restrict__ Wq2, const float* __restrict__ Wk2,
    const float* __restrict__ Wv2, const float* __restrict__ Wtd,
    const float* __restrict__ Wu1, const float* __restrict__ Wc1,
    unsigned short* __restrict__ whi) {
  int blk = blockIdx.x;
  if (blk < 32) {
    int i = blk * 256 + threadIdx.x;  // 8192
    float x = pts[3 * i], y = pts[3 * i + 1], z = pts[3 * i + 2];
    soa[i] = make_float4(x, y, z, x * x + y * y + z * z);
    return;
  }
  int t = (blk - 32) * 256 + threadIdx.x;  // < 933888
  float v;
  if (t < 16384) {
    int n = t >> 6, k = t & 63;
    if (n < 128) v = We2[k * 128 + n] - We2[(k + 64) * 128 + n];
    else         v = We2[(k + 64) * 128 + (n - 128)];
  } else if (t < 114688) {
    int e = t - 16384;
    int n = e >> 7, k = e & 127;
    if (n < 256)      v = Wq1[k * 256 + n];
    else if (n < 512) v = Wk1[k * 256 + (n - 256)];
    else              v = Wv1[k * 256 + (n - 512)];
  } else if (t < 507904) {
    int e = t - 114688;
    int n = e >> 8, k = e & 255;
    if (n < 512)       v = Wq2[k * 512 + n];
    else if (n < 1024) v = Wk2[k * 512 + (n - 512)];
    else               v = Wv2[k * 512 + (n - 1024)];
  } else if (t < 770048) {
    int e = t - 507904;
    int n = e >> 9, k = e & 511;
    v = Wtd[(3 + k) * 512 + n];
  } else if (t < 901120) {
    int e = t - 770048;
    int n = e >> 9, k = e & 511;
    v = Wu1[k * 256 + n];
  } else {
    int e = t - 901120;
    int n = e >> 8, k = e & 255;
    v = Wc1[k * 128 + n];
  }
  whi[t] = f2h(v);
}

// ---------------- knn (frozen structure: 2 queries/wave, 512 blocks) -------
__device__ __forceinline__ void bitonic_lex64(float& d, int& i, int lane) {
#pragma unroll
  for (int k = 2; k <= 64; k <<= 1) {
#pragma unroll
    for (int j = k >> 1; j >= 1; j >>= 1) {
      float od = __shfl_xor(d, j);
      int oi = __shfl_xor(i, j);
      bool takeMin = (((lane & k) == 0) == ((lane & j) == 0));
      bool less = lexless(od, oi, d, i);
      if (takeMin == less) { d = od; i = oi; }
    }
  }
}

__device__ __forceinline__ void insert1(float cd, int ci, int lane,
                                        float& td, int& ti) {
  int p = __popcll(__ballot(lexless(td, ti, cd, ci)));
  if (p < 16) {
    float ud = __shfl_up(td, 1);
    int ui = __shfl_up(ti, 1);
    float ntd = td; int nti = ti;
    if (lane > p && lane < 16) { ntd = ud; nti = ui; }
    if (lane == p) { ntd = cd; nti = ci; }
    td = ntd; ti = nti;
  }
}

__global__ __launch_bounds__(512) void knn_k(const float4* __restrict__ soa,
                                             int* __restrict__ idxout) {
  __shared__ float4 sp[2048];
  __shared__ float cb_d[16][KCAP];
  __shared__ int cb_i[16][KCAP];
  __shared__ int ccnt[16];
  const int lane = threadIdx.x & 63;
  const int wid = threadIdx.x >> 6;
  const int q0 = blockIdx.x * 16 + wid * 2;
  const float4 qa = soa[q0];
  const float4 qb = soa[q0 + 1];
  const float ax2 = -2.f * qa.x, ay2 = -2.f * qa.y, az2 = -2.f * qa.z;
  const float bx2 = -2.f * qb.x, by2 = -2.f * qb.y, bz2 = -2.f * qb.z;
  const float INF = __int_as_float(0x7f800000);
  if (lane < 2) ccnt[wid * 2 + lane] = 0;

  // ---- pass A ----
  float mda = INF, mdb = INF;
  int mia = 0x7fffffff, mib = 0x7fffffff;
  for (int ch = 0; ch < 4; ++ch) {
    __syncthreads();
    for (int j = 0; j < 4; ++j) {
      int e = j * 512 + threadIdx.x;
      sp[e] = soa[ch * 2048 + e];
    }
    __syncthreads();
#pragma unroll 4
    for (int c = 0; c < 32; ++c) {
      const float4 P = sp[c * 64 + lane];
      const int gidx = ch * 2048 + c * 64 + lane;
      float da = fmaf(ax2, P.x, qa.w);
      da = fmaf(ay2, P.y, da);
      da = fmaf(az2, P.z, da);
      da += P.w;
      float db = fmaf(bx2, P.x, qb.w);
      db = fmaf(by2, P.y, db);
      db = fmaf(bz2, P.z, db);
      db += P.w;
      if (da < mda) { mda = da; mia = gidx; }
      if (db < mdb) { mdb = db; mib = gidx; }
    }
  }
  const int owna = mia;
  const int ownb = mib;
  float sda = mda; int sia = mia;
  float sdb = mdb; int sib = mib;
  bitonic_lex64(sda, sia, lane);
  bitonic_lex64(sdb, sib, lane);

  float tda = (lane < 16) ? sda : INF;
  int tia = (lane < 16) ? sia : 0x7fffffff;
  float tdb = (lane < 16) ? sdb : INF;
  int tib = (lane < 16) ? sib : 0x7fffffff;
  float Tda = __shfl(sda, 15); int Tia = __shfl(sia, 15);
  float Tdb = __shfl(sdb, 15); int Tib = __shfl(sib, 15);
  const float taua = Tda + fabsf(Tda) * 1e-5f + 1e-12f;
  const float taub = Tdb + fabsf(Tdb) * 1e-5f + 1e-12f;

  // ---- pass B: collect stragglers; chunk order {3,0,1,2} ----
  // LDS still holds ch3 from pass A (cb/ccnt are separate arrays; bitonic is
  // register-only), so the first iteration skips staging entirely.
  for (int cidx = 0; cidx < 4; ++cidx) {
    const int ch = (cidx == 0) ? 3 : (cidx - 1);
    if (cidx != 0) {
      __syncthreads();
      for (int j = 0; j < 4; ++j) {
        int e = j * 512 + threadIdx.x;
        sp[e] = soa[ch * 2048 + e];
      }
      __syncthreads();
    }
#pragma unroll 4
    for (int c = 0; c < 32; ++c) {
      const float4 P = sp[c * 64 + lane];
      const int gidx = ch * 2048 + c * 64 + lane;
      float da = fmaf(ax2, P.x, qa.w);
      da = fmaf(ay2, P.y, da);
      da = fmaf(az2, P.z, da);
      da += P.w;
      float db = fmaf(bx2, P.x, qb.w);
      db = fmaf(by2, P.y, db);
      db = fmaf(bz2, P.z, db);
      db += P.w;
      if (da <= taua && gidx != owna) {
        int slot = atomicAdd(&ccnt[wid * 2], 1);
        if (slot < KCAP) { cb_d[wid * 2][slot] = da; cb_i[wid * 2][slot] = gidx; }
      }
      if (db <= taub && gidx != ownb) {
        int slot = atomicAdd(&ccnt[wid * 2 + 1], 1);
        if (slot < KCAP) { cb_d[wid * 2 + 1][slot] = db; cb_i[wid * 2 + 1][slot] = gidx; }
      }
    }
  }

  // ---- drain query a ----
  int na = ccnt[wid * 2];
  if (na <= KCAP) {
    for (int k2 = 0; k2 < na; ++k2) {
      float cd = cb_d[wid * 2][k2];
      int ci = cb_i[wid * 2][k2];
      if (lexless(cd, ci, Tda, Tia)) {
        insert1(cd, ci, lane, tda, tia);
        Tda = __shfl(tda, 15); Tia = __shfl(tia, 15);
      }
    }
  } else {
    tda = INF; tia = 0x7fffffff; Tda = INF; Tia = 0x7fffffff;
    for (int base = 0; base < 8192; base += 64) {
      const float4 P = soa[base + lane];
      float d = fmaf(ax2, P.x, qa.w);
      d = fmaf(ay2, P.y, d);
      d = fmaf(az2, P.z, d);
      d += P.w;
      const int gidx = base + lane;
      u64 mk = __ballot(d <= taua && lexless(d, gidx, Tda, Tia));
      while (mk) {
        int s = (int)__builtin_ctzll(mk);
        mk &= mk - 1;
        float cd = __shfl(d, s);
        int ci = __shfl(gidx, s);
        insert1(cd, ci, lane, tda, tia);
      }
      Tda = __shfl(tda, 15); Tia = __shfl(tia, 15);
    }
  }
  // ---- drain query b ----
  int nb = ccnt[wid * 2 + 1];
  if (nb <= KCAP) {
    for (int k2 = 0; k2 < nb; ++k2) {
      float cd = cb_d[wid * 2 + 1][k2];
      int ci = cb_i[wid * 2 + 1][k2];
      if (lexless(cd, ci, Tdb, Tib)) {
        insert1(cd, ci, lane, tdb, tib);
        Tdb = __shfl(tdb, 15); Tib = __shfl(tib, 15);
      }
    }
  } else {
    tdb = INF; tib = 0x7fffffff; Tdb = INF; Tib = 0x7fffffff;
    for (int base = 0; base < 8192; base += 64) {
      const float4 P = soa[base + lane];
      float d = fmaf(bx2, P.x, qb.w);
      d = fmaf(by2, P.y, d);
      d = fmaf(bz2, P.z, d);
      d += P.w;
      const int gidx = base + lane;
      u64 mk = __ballot(d <= taub && lexless(d, gidx, Tdb, Tib));
      while (mk) {
        int s = (int)__builtin_ctzll(mk);
        mk &= mk - 1;
        float cd = __shfl(d, s);
        int ci = __shfl(gidx, s);
        insert1(cd, ci, lane, tdb, tib);
      }
      Tdb = __shfl(tdb, 15); Tib = __shfl(tib, 15);
    }
  }
  if (lane < 16) {
    idxout[q0 * 16 + lane] = tia & 8191;
    idxout[(q0 + 1) * 16 + lane] = tib & 8191;
  }
}

// ---------------- edge conv ----------------
__global__ __launch_bounds__(256) void proj1_k(const float4* __restrict__ soa,
                                               const float* __restrict__ We1,
                                               unsigned short* __restrict__ bz1) {
  int t = blockIdx.x * 256 + threadIdx.x;  // 8192*32
  int i = t >> 5, g = t & 31;
  float4 P = soa[i];
  us4 o;
#pragma unroll
  for (int j = 0; j < 4; ++j) {
    int c = 4 * g + j;
    float v;
    if (c < 64) {
      v = P.x * (We1[c] - We1[192 + c]) + P.y * (We1[64 + c] - We1[256 + c]) +
          P.z * (We1[128 + c] - We1[320 + c]);
    } else {
      int cc = c & 63;
      v = P.x * We1[192 + cc] + P.y * We1[256 + cc] + P.z * We1[320 + cc];
    }
    o[j] = f2h(v);
  }
  *(us4*)&bz1[(size_t)i * 128 + 4 * g] = o;
}

template <int C>
__global__ __launch_bounds__(256) void ec_gm_k(const unsigned short* __restrict__ bz,
                                               const int* __restrict__ idx,
                                               const float* __restrict__ s,
                                               const float* __restrict__ b,
                                               unsigned short* __restrict__ xo) {
  constexpr int C4 = C / 4;
  int t = blockIdx.x * 256 + threadIdx.x;  // NP*C4
  int i = t / C4, q = t % C4;
  us4 b4 = *(const us4*)&bz[(size_t)i * (2 * C) + q * 4];
  float bx = h2f(b4[0]), by = h2f(b4[1]), bz2v = h2f(b4[2]), bw = h2f(b4[3]);
  float4 scl = *(const float4*)&s[q * 4];
  float4 bia = *(const float4*)&b[q * 4];
  float ax = 0.f, ay = 0.f, az = 0.f, aw = 0.f;
  const int* ip = idx + i * 16;
#pragma unroll
  for (int n = 0; n < 16; ++n) {
    int j = ip[n];
    us4 z4 = *(const us4*)&bz[(size_t)j * (2 * C) + C + q * 4];
    ax = fmaxf(ax, (bx + h2f(z4[0])) * scl.x + bia.x);
    ay = fmaxf(ay, (by + h2f(z4[1])) * scl.y + bia.y);
    az = fmaxf(az, (bz2v + h2f(z4[2])) * scl.z + bia.z);
    aw = fmaxf(aw, (bw + h2f(z4[3])) * scl.w + bia.w);
  }
  us4 o;
  o[0] = f2h(ax); o[1] = f2h(ay); o[2] = f2h(az); o[3] = f2h(aw);
  *(us4*)&xo[(size_t)i * C + q * 4] = o;
}

// ---------------- fused attention (q fp16, dot2 logits) ----------------
template <int C>
__global__ __launch_bounds__(256) void attn_fused_k(const unsigned short* __restrict__ qh,
                                                    const unsigned short* __restrict__ kvb,
                                                    const int* __restrict__ idx,
                                                    const float* __restrict__ s,
                                                    const float* __restrict__ b,
                                                    unsigned short* __restrict__ xo,
                                                    float scale) {
  int i = blockIdx.x * 4 + (threadIdx.x >> 6);
  int lane = threadIdx.x & 63;
  constexpr int G = C / 256;
  int jreg = (lane < 16) ? idx[i * 16 + lane] : 0;
  uint2 qreg[G];
#pragma unroll
  for (int g = 0; g < G; ++g)
    qreg[g] = *(const uint2*)&qh[(size_t)i * C + 4 * lane + 256 * g];
  float lg[16];
#pragma unroll
  for (int n = 0; n < 16; ++n) {
    int j = __shfl(jreg, n);
    const unsigned short* kr = kvb + (size_t)j * (2 * C);
    float ssum = 0.f;
#pragma unroll
    for (int g = 0; g < G; ++g) {
      uint2 kk = *(const uint2*)&kr[4 * lane + 256 * g];
#if __has_builtin(__builtin_amdgcn_fdot2)
      ssum = __builtin_amdgcn_fdot2(__builtin_bit_cast(h2v, kk.x),
                                    __builtin_bit_cast(h2v, qreg[g].x), ssum, false);
      ssum = __builtin_amdgcn_fdot2(__builtin_bit_cast(h2v, kk.y),
                                    __builtin_bit_cast(h2v, qreg[g].y), ssum, false);
#else
      us4 k4 = __builtin_bit_cast(us4, kk);
      us4 q4 = __builtin_bit_cast(us4, qreg[g]);
      ssum += h2f(q4[0]) * h2f(k4[0]) + h2f(q4[1]) * h2f(k4[1]) +
              h2f(q4[2]) * h2f(k4[2]) + h2f(q4[3]) * h2f(k4[3]);
#endif
    }
    lg[n] = ssum;
  }
#pragma unroll
  for (int n = 0; n < 16; ++n) {
    float vv = lg[n];
    for (int o = 32; o >= 1; o >>= 1) vv += __shfl_xor(vv, o);
    lg[n] = vv * scale;
  }
  float m = lg[0];
#pragma unroll
  for (int n = 1; n < 16; ++n) m = fmaxf(m, lg[n]);
  float ssum = 0.f;
#pragma unroll
  for (int n = 0; n < 16; ++n) { lg[n] = __expf(lg[n] - m); ssum += lg[n]; }
  float inv = 1.f / ssum;
#pragma unroll
  for (int n = 0; n < 16; ++n) lg[n] *= inv;

  float acc[4 * G];
#pragma unroll
  for (int e = 0; e < 4 * G; ++e) acc[e] = 0.f;
#pragma unroll
  for (int n = 0; n < 16; ++n) {
    int j = __shfl(jreg, n);
    const unsigned short* vr = kvb + (size_t)j * (2 * C) + C;
    float w = lg[n];
#pragma unroll
    for (int g = 0; g < G; ++g) {
      us4 v4 = *(const us4*)&vr[4 * lane + 256 * g];
      acc[4 * g + 0] += w * h2f(v4[0]);
      acc[4 * g + 1] += w * h2f(v4[1]);
      acc[4 * g + 2] += w * h2f(v4[2]);
      acc[4 * g + 3] += w * h2f(v4[3]);
    }
  }
#pragma unroll
  for (int g = 0; g < G; ++g) {
    int c0 = 4 * lane + 256 * g;
    float4 scl = *(const float4*)&s[c0];
    float4 bia = *(const float4*)&b[c0];
    us4 o;
    o[0] = f2h(fmaxf(acc[4 * g + 0] * scl.x + bia.x, 0.f));
    o[1] = f2h(fmaxf(acc[4 * g + 1] * scl.y + bia.y, 0.f));
    o[2] = f2h(fmaxf(acc[4 * g + 2] * scl.z + bia.z, 0.f));
    o[3] = f2h(fmaxf(acc[4 * g + 3] * scl.w + bia.w, 0.f));
    *(us4*)&xo[(size_t)i * C + c0] = o;
  }
}

// ---------------- down stage ----------------
__global__ __launch_bounds__(256) void down_gm_k(const unsigned short* __restrict__ vbuf,
                                                 const float4* __restrict__ soa,
                                                 const float* __restrict__ Wtd,
                                                 const int* __restrict__ idx,
                                                 const float* __restrict__ sd,
                                                 const float* __restrict__ bd,
                                                 unsigned short* __restrict__ xd) {
  int t = blockIdx.x * 256 + threadIdx.x;  // 2048*128
  int i = t >> 7, q = t & 127;
  int qi = 4 * i;
  float4 qp = soa[qi];
  float4 w0 = *(const float4*)&Wtd[q * 4];
  float4 w1 = *(const float4*)&Wtd[512 + q * 4];
  float4 w2 = *(const float4*)&Wtd[1024 + q * 4];
  float px = qp.x * w0.x + qp.y * w1.x + qp.z * w2.x;
  float py = qp.x * w0.y + qp.y * w1.y + qp.z * w2.y;
  float pz = qp.x * w0.z + qp.y * w1.z + qp.z * w2.z;
  float pw2 = qp.x * w0.w + qp.y * w1.w + qp.z * w2.w;
  float4 scl = *(const float4*)&sd[q * 4];
  float4 bia = *(const float4*)&bd[q * 4];
  float ax = 0.f, ay = 0.f, az = 0.f, aw = 0.f;
  const int* ip = idx + qi * 16;
#pragma unroll
  for (int n = 0; n < 16; ++n) {
    int j = ip[n];
    us4 v4 = *(const us4*)&vbuf[(size_t)j * 512 + q * 4];
    ax = fmaxf(ax, (h2f(v4[0]) - px) * scl.x + bia.x);
    ay = fmaxf(ay, (h2f(v4[1]) - py) * scl.y + bia.y);
    az = fmaxf(az, (h2f(v4[2]) - pz) * scl.z + bia.z);
    aw = fmaxf(aw, (h2f(v4[3]) - pw2) * scl.w + bia.w);
  }
  us4 o;
  o[0] = f2h(ax); o[1] = f2h(ay); o[2] = f2h(az); o[3] = f2h(aw);
  *(us4*)&xd[(size_t)i * 512 + q * 4] = o;
}

// 128 blocks x 512 thr; block b sums rows [b*16, b*16+16).
__global__ __launch_bounds__(512) void colsum_k(const unsigned short* __restrict__ xd,
                                                float* __restrict__ part) {
  int b = blockIdx.x;           // 128
  int c = threadIdx.x;          // 512
  float s = 0.f;
  for (int r = b * 16; r < (b + 1) * 16; ++r) s += h2f(xd[(size_t)r * 512 + c]);
  part[b * 512 + c] = s;
}

// 16 blocks x 256 thr; block b owns outputs [b*16, b*16+16).
__global__ __launch_bounds__(256) void gterm_k(const float* __restrict__ part,
                                               const float* __restrict__ Wu2,
                                               const float* __restrict__ su2,
                                               const float* __restrict__ bu2,
                                               float* __restrict__ gterm) {
  __shared__ float gm[512];
  int tid = threadIdx.x;
  for (int c = tid; c < 512; c += 256) {
    float s = 0.f;
#pragma unroll
    for (int b = 0; b < 128; ++b) s += part[b * 512 + c];
    gm[c] = s * (1.f / 2048.f);
  }
  __syncthreads();
  int o = blockIdx.x * 16 + (tid >> 4);
  int kseg = tid & 15;
  float s = 0.f;
#pragma unroll 8
  for (int k = kseg * 32; k < kseg * 32 + 32; ++k) s += gm[k] * Wu2[k * 256 + o];
  s += __shfl_xor(s, 1);
  s += __shfl_xor(s, 2);
  s += __shfl_xor(s, 4);
  s += __shfl_xor(s, 8);
  if (kseg == 0) gterm[o] = s * su2[o] + bu2[o];
}

// ---------------- MFMA GEMM (fp16, 128x128 block, 64x64/wave) ----------------
// MODE 0: fp16 out. MODE 1: fp16 out += p@Wtd[0:3]. MODE 2: fp16
// relu(acc*s1+b1+s2). MODE 3: fp32 relu((acc+b1)*s1+s2). MODE 4: q fp16 +
// kv fp16 mixed (q cols < Cq -> Ch).
#define LDSROW 80
template <int MODE>
__global__ __launch_bounds__(256) void gemm_mfma(
    const unsigned short* __restrict__ A,
    const unsigned short* __restrict__ B,
    float* __restrict__ Cf, unsigned short* __restrict__ Ch,
    int M, int N, int K,
    const float4* __restrict__ soaD, const float* __restrict__ wtd,
    const float* __restrict__ s1, const float* __restrict__ b1,
    const float* __restrict__ s2, int Cq, unsigned short* __restrict__ kvb) {
  __shared__ __align__(16) char smem[2 * 128 * LDSROW];
  char* A_s = smem;
  char* B_s = smem + 128 * LDSROW;

  const int tid = threadIdx.x;
  const int lane = tid & 63;
  const int wid = tid >> 6;
  const int wm = wid >> 1, wn = wid & 1;
  const int bm = blockIdx.y * 128, bn = blockIdx.x * 128;
  const int r16 = lane & 15, kb = lane >> 4;

  f32x4 acc[4][4];
#pragma unroll
  for (int a = 0; a < 4; ++a)
#pragma unroll
    for (int b = 0; b < 4; ++b) acc[a][b] = (f32x4)(0.f);

  for (int k0 = 0; k0 < K; k0 += 32) {
    __syncthreads();
#pragma unroll
    for (int qq = 0; qq < 2; ++qq) {
      int idx8 = qq * 256 + tid;
      int row = idx8 >> 2, sq = idx8 & 3;
      size_t goA = (size_t)(bm + row) * K + k0 + sq * 8;
      size_t goB = (size_t)(bn + row) * K + k0 + sq * 8;
      ushort8 a_v = *(const ushort8*)&A[goA];
      ushort8 b_v = *(const ushort8*)&B[goB];
      *(ushort8*)(A_s + row * LDSROW + sq * 16) = a_v;
      *(ushort8*)(B_s + row * LDSROW + sq * 16) = b_v;
    }
    __syncthreads();

    half8 ah[4];
#pragma unroll
    for (int mi = 0; mi < 4; ++mi) {
      int off = (wm * 64 + mi * 16 + r16) * LDSROW + kb * 16;
      ah[mi] = *(const half8*)(A_s + off);
    }
#pragma unroll
    for (int ni = 0; ni < 4; ++ni) {
      int off = (wn * 64 + ni * 16 + r16) * LDSROW + kb * 16;
      half8 bh = *(const half8*)(B_s + off);
#pragma unroll
      for (int mi = 0; mi < 4; ++mi) {
        acc[mi][ni] = __builtin_amdgcn_mfma_f32_16x16x32_f16(ah[mi], bh, acc[mi][ni], 0, 0, 0);
      }
    }
  }

#pragma unroll
  for (int mi = 0; mi < 4; ++mi) {
#pragma unroll
    for (int ni = 0; ni < 4; ++ni) {
      int r0 = bm + wm * 64 + mi * 16 + (lane >> 4) * 4;
      int cc = bn + wn * 64 + ni * 16 + (lane & 15);
      float w0 = 0.f, w1 = 0.f, w2 = 0.f;
      if (MODE == 1) { w0 = wtd[cc]; w1 = wtd[512 + cc]; w2 = wtd[1024 + cc]; }
#pragma unroll
      for (int j = 0; j < 4; ++j) {
        float vv = acc[mi][ni][j];
        int row = r0 + j;
        if (MODE == 1) {
          float4 P = soaD[row];
          vv += P.x * w0 + P.y * w1 + P.z * w2;
        }
        if (MODE == 2) vv = fmaxf(vv * s1[cc] + b1[cc] + s2[cc], 0.f);
        if (MODE == 3) vv = fmaxf((vv + b1[cc]) * s1[cc] + s2[cc], 0.f);
        if (MODE == 0 || MODE == 1 || MODE == 2) {
          Ch[(size_t)row * N + cc] = f2h(vv);
        } else if (MODE == 4) {
          if (cc < Cq) Ch[(size_t)row * Cq + cc] = f2h(vv);
          else kvb[(size_t)row * (2 * Cq) + (cc - Cq)] = f2h(vv);
        } else {
          Cf[(size_t)row * N + cc] = vv;
        }
      }
    }
  }
}

// ---------------- final ----------------
__global__ __launch_bounds__(256) void out_k(const float* __restrict__ h,
                                             const float* __restrict__ Wc2,
                                             const float* __restrict__ bc2,
                                             float* __restrict__ out) {
  int t = blockIdx.x * 256 + threadIdx.x;  // 49152
  int pair = t >> 2, kq = t & 3;           // pair < 12288
  int i = pair / 6, o = pair % 6;
  float s = 0.f;
#pragma unroll 8
  for (int m = kq * 32; m < kq * 32 + 32; ++m) s += h[i * 128 + m] * Wc2[m * 6 + o];
  s += __shfl_xor(s, 1);
  s += __shfl_xor(s, 2);
  if (kq == 0) out[pair] = s + bc2[o];
}

extern "C" void kernel_launch(void* const* d_in, const int* in_sizes, int n_in,
                              void* d_out, int out_size, void* d_ws, size_t ws_size,
                              hipStream_t stream) {
  const float* pts = (const float*)d_in[0];
  const float* We1 = (const float*)d_in[1];
  const float* se1 = (const float*)d_in[2];
  const float* be1 = (const float*)d_in[3];
  const float* We2 = (const float*)d_in[4];
  const float* se2 = (const float*)d_in[5];
  const float* be2 = (const float*)d_in[6];
  const float* Wq1 = (const float*)d_in[7];
  const float* Wk1 = (const float*)d_in[8];
  const float* Wv1 = (const float*)d_in[9];
  const float* sa1 = (const float*)d_in[10];
  const float* ba1 = (const float*)d_in[11];
  const float* Wq2 = (const float*)d_in[12];
  const float* Wk2 = (const float*)d_in[13];
  const float* Wv2 = (const float*)d_in[14];
  const float* sa2 = (const float*)d_in[15];
  const float* ba2 = (const float*)d_in[16];
  const float* Wtd = (const float*)d_in[17];
  const float* sd  = (const float*)d_in[18];
  const float* bd  = (const float*)d_in[19];
  const float* Wu1 = (const float*)d_in[20];
  const float* su1 = (const float*)d_in[21];
  const float* bu1 = (const float*)d_in[22];
  const float* Wu2 = (const float*)d_in[23];
  const float* su2 = (const float*)d_in[24];
  const float* bu2 = (const float*)d_in[25];
  const float* Wc1 = (const float*)d_in[26];
  const float* bc1 = (const float*)d_in[27];
  const float* sc  = (const float*)d_in[28];
  const float* bc  = (const float*)d_in[29];
  const float* Wc2 = (const float*)d_in[30];
  const float* bc2 = (const float*)d_in[31];

  float* ws = (float*)d_ws;
  if (ws_size < (size_t)16703744 * 4) return;  // ~66.8 MB
  float* soa   = ws;                      // 32768
  int*   idx   = (int*)(ws + 32768);      // 131072 ints
  float* gpart = ws + 163840;             // 65536 (128x512, ex-attw slot)
  float* gterm = ws + 303104;             // 256
  unsigned short* wthi = (unsigned short*)(ws + 303360);   // 933888 ush
  unsigned short* x1   = (unsigned short*)(ws + 1237248);  // 524288 ush
  unsigned short* x2   = (unsigned short*)(ws + 1499392);  // 1048576 ush
  unsigned short* x3   = (unsigned short*)(ws + 2023680);  // 2097152 ush
  unsigned short* x4   = (unsigned short*)(ws + 3072256);  // 4194304 ush
  unsigned short* xd   = (unsigned short*)(ws + 5169408);  // 1048576 ush
  unsigned short* xu   = (unsigned short*)(ws + 5693696);  // 524288 ush
  unsigned short* bzb  = (unsigned short*)(ws + 5955840);  // bz fp16 (<=4 MB)
  float* qf    = ws + 8052992;            // 4194304 f (qh fp16 / vbuf fp16)
  unsigned short* qh   = (unsigned short*)qf;
  unsigned short* vbuf = (unsigned short*)qf;
  unsigned short* kvb = (unsigned short*)(ws + 12247296);  // 8388608 ush
  float* hbuf  = ws + 16441600;           // 262144 f

  prep_all_k<<<3680, 256, 0, stream>>>(pts, (float4*)soa, We2, Wq1, Wk1, Wv1,
                                       Wq2, Wk2, Wv2, Wtd, Wu1, Wc1, wthi);
  knn_k<<<512, 512, 0, stream>>>((const float4*)soa, idx);

  // edge conv 1: bz1 fp16; x1 fp16
  proj1_k<<<1024, 256, 0, stream>>>((const float4*)soa, We1, bzb);
  ec_gm_k<64><<<512, 256, 0, stream>>>(bzb, idx, se1, be1, x1);

  // edge conv 2: bz2 = x1 @ wcat2 (fp16, N=256); x2 fp16
  gemm_mfma<0><<<dim3(2, 64), 256, 0, stream>>>(x1, wthi,
      nullptr, bzb, NP, 256, 64, nullptr, nullptr, nullptr, nullptr, nullptr, 0, nullptr);
  ec_gm_k<128><<<1024, 256, 0, stream>>>(bzb, idx, se2, be2, x2);

  // attn 1: q fp16 + kv fp16 (N=768)
  gemm_mfma<4><<<dim3(6, 64), 256, 0, stream>>>(x2, wthi + 16384,
      nullptr, qh, NP, 768, 128, nullptr, nullptr, nullptr, nullptr, nullptr, 256, kvb);
  attn_fused_k<256><<<2048, 256, 0, stream>>>(qh, kvb, idx, sa1, ba1, x3, 0.0625f);

  // attn 2 (N=1536)
  gemm_mfma<4><<<dim3(12, 64), 256, 0, stream>>>(x3, wthi + 114688,
      nullptr, qh, NP, 1536, 256, nullptr, nullptr, nullptr, nullptr, nullptr, 512, kvb);
  attn_fused_k<512><<<2048, 256, 0, stream>>>(qh, kvb, idx, sa2, ba2, x4, 0.04419417382415922f);

  // down: vbuf = x4 @ wtdx + p@Wtd[0:3], fp16 (N=512)
  gemm_mfma<1><<<dim3(4, 64), 256, 0, stream>>>(x4, wthi + 507904,
      nullptr, vbuf, NP, 512, 512, (const float4*)soa, Wtd, nullptr, nullptr, nullptr, 0, nullptr);
  down_gm_k<<<1024, 256, 0, stream>>>(vbuf, (const float4*)soa, Wtd, idx, sd, bd, xd);

  // global mean term
  colsum_k<<<128, 512, 0, stream>>>(xd, gpart);
  gterm_k<<<16, 256, 0, stream>>>(gpart, Wu2, su2, bu2, gterm);

  // xu (N=256)
  gemm_mfma<2><<<dim3(2, 16), 256, 0, stream>>>(xd, wthi + 770048,
      nullptr, xu, NDOWN, 256, 512, nullptr, nullptr, su1, bu1, gterm, 0, nullptr);
  // h (N=128)
  gemm_mfma<3><<<dim3(1, 16), 256, 0, stream>>>(xu, wthi + 901120,
      hbuf, nullptr, NDOWN, 128, 256, nullptr, nullptr, sc, bc1, bc, 0, nullptr);
  // out
  out_k<<<192, 256, 0, stream>>>(hbuf, Wc2, bc2, (float*)d_out);
}

// Round 16
// 241.782 us; speedup vs baseline: 1.1019x; 1.1019x over previous
//
#include <hip/hip_runtime.h>

// DefectNet forward. Round 16 = round 14 (233.1us measured) with gterm_k
// reverted to the pre-round-9 coalesced 1-block design (round 15 exposed the
// kseg-split Wu2 access as uncoalesced: 68us at 0.6% occupancy).
// knn frozen; colsum back to 16 blocks.

#define NP 8192
#define NDOWN 2048
#define KCAP 32

typedef unsigned long long u64;
typedef __attribute__((ext_vector_type(8))) _Float16 half8;
typedef __attribute__((ext_vector_type(4))) unsigned short us4;
typedef __attribute__((ext_vector_type(8))) unsigned short ushort8;
typedef __attribute__((ext_vector_type(4))) float f32x4;

__device__ __forceinline__ bool lexless(float ad, int ai, float bd, int bi) {
  return ad < bd || (ad == bd && ai < bi);
}

__device__ __forceinline__ unsigned short f2h(float x) {
  _Float16 h = (_Float16)x;
  return __builtin_bit_cast(unsigned short, h);
}
__device__ __forceinline__ float h2f(unsigned short u) {
  return (float)__builtin_bit_cast(_Float16, u);
}

// ---------------- prep (points + weight transpose, merged) ----------------
__global__ __launch_bounds__(256) void prep_all_k(
    const float* __restrict__ pts, float4* __restrict__ soa,
    const float* __restrict__ We2, const float* __restrict__ Wq1,
    const float* __restrict__ Wk1, const float* __restrict__ Wv1,
    const float* __restrict__ Wq2, const float* __restrict__ Wk2,
    const float* __restrict__ Wv2, const float* __restrict__ Wtd,
    const float* __restrict__ Wu1, const float* __restrict__ Wc1,
    unsigned short* __restrict__ whi) {
  int blk = blockIdx.x;
  if (blk < 32) {
    int i = blk * 256 + threadIdx.x;  // 8192
    float x = pts[3 * i], y = pts[3 * i + 1], z = pts[3 * i + 2];
    soa[i] = make_float4(x, y, z, x * x + y * y + z * z);
    return;
  }
  int t = (blk - 32) * 256 + threadIdx.x;  // < 933888
  float v;
  if (t < 16384) {
    int n = t >> 6, k = t & 63;
    if (n < 128) v = We2[k * 128 + n] - We2[(k + 64) * 128 + n];
    else         v = We2[(k + 64) * 128 + (n - 128)];
  } else if (t < 114688) {
    int e = t - 16384;
    int n = e >> 7, k = e & 127;
    if (n < 256)      v = Wq1[k * 256 + n];
    else if (n < 512) v = Wk1[k * 256 + (n - 256)];
    else              v = Wv1[k * 256 + (n - 512)];
  } else if (t < 507904) {
    int e = t - 114688;
    int n = e >> 8, k = e & 255;
    if (n < 512)       v = Wq2[k * 512 + n];
    else if (n < 1024) v = Wk2[k * 512 + (n - 512)];
    else               v = Wv2[k * 512 + (n - 1024)];
  } else if (t < 770048) {
    int e = t - 507904;
    int n = e >> 9, k = e & 511;
    v = Wtd[(3 + k) * 512 + n];
  } else if (t < 901120) {
    int e = t - 770048;
    int n = e >> 9, k = e & 511;
    v = Wu1[k * 256 + n];
  } else {
    int e = t - 901120;
    int n = e >> 8, k = e & 255;
    v = Wc1[k * 128 + n];
  }
  whi[t] = f2h(v);
}

// ---------------- knn (frozen: 2 queries/wave, 512 blocks) ----------------
__device__ __forceinline__ void bitonic_lex64(float& d, int& i, int lane) {
#pragma unroll
  for (int k = 2; k <= 64; k <<= 1) {
#pragma unroll
    for (int j = k >> 1; j >= 1; j >>= 1) {
      float od = __shfl_xor(d, j);
      int oi = __shfl_xor(i, j);
      bool takeMin = (((lane & k) == 0) == ((lane & j) == 0));
      bool less = lexless(od, oi, d, i);
      if (takeMin == less) { d = od; i = oi; }
    }
  }
}

__device__ __forceinline__ void insert1(float cd, int ci, int lane,
                                        float& td, int& ti) {
  int p = __popcll(__ballot(lexless(td, ti, cd, ci)));
  if (p < 16) {
    float ud = __shfl_up(td, 1);
    int ui = __shfl_up(ti, 1);
    float ntd = td; int nti = ti;
    if (lane > p && lane < 16) { ntd = ud; nti = ui; }
    if (lane == p) { ntd = cd; nti = ci; }
    td = ntd; ti = nti;
  }
}

__global__ __launch_bounds__(512) void knn_k(const float4* __restrict__ soa,
                                             int* __restrict__ idxout) {
  __shared__ float4 sp[2048];
  __shared__ float cb_d[16][KCAP];
  __shared__ int cb_i[16][KCAP];
  __shared__ int ccnt[16];
  const int lane = threadIdx.x & 63;
  const int wid = threadIdx.x >> 6;
  const int q0 = blockIdx.x * 16 + wid * 2;
  const float4 qa = soa[q0];
  const float4 qb = soa[q0 + 1];
  const float ax2 = -2.f * qa.x, ay2 = -2.f * qa.y, az2 = -2.f * qa.z;
  const float bx2 = -2.f * qb.x, by2 = -2.f * qb.y, bz2 = -2.f * qb.z;
  const float INF = __int_as_float(0x7f800000);
  if (lane < 2) ccnt[wid * 2 + lane] = 0;

  // ---- pass A ----
  float mda = INF, mdb = INF;
  int mia = 0x7fffffff, mib = 0x7fffffff;
  for (int ch = 0; ch < 4; ++ch) {
    __syncthreads();
    for (int j = 0; j < 4; ++j) {
      int e = j * 512 + threadIdx.x;
      sp[e] = soa[ch * 2048 + e];
    }
    __syncthreads();
#pragma unroll 4
    for (int c = 0; c < 32; ++c) {
      const float4 P = sp[c * 64 + lane];
      const int gidx = ch * 2048 + c * 64 + lane;
      float da = fmaf(ax2, P.x, qa.w);
      da = fmaf(ay2, P.y, da);
      da = fmaf(az2, P.z, da);
      da += P.w;
      float db = fmaf(bx2, P.x, qb.w);
      db = fmaf(by2, P.y, db);
      db = fmaf(bz2, P.z, db);
      db += P.w;
      if (da < mda) { mda = da; mia = gidx; }
      if (db < mdb) { mdb = db; mib = gidx; }
    }
  }
  const int owna = mia;
  const int ownb = mib;
  float sda = mda; int sia = mia;
  float sdb = mdb; int sib = mib;
  bitonic_lex64(sda, sia, lane);
  bitonic_lex64(sdb, sib, lane);

  float tda = (lane < 16) ? sda : INF;
  int tia = (lane < 16) ? sia : 0x7fffffff;
  float tdb = (lane < 16) ? sdb : INF;
  int tib = (lane < 16) ? sib : 0x7fffffff;
  float Tda = __shfl(sda, 15); int Tia = __shfl(sia, 15);
  float Tdb = __shfl(sdb, 15); int Tib = __shfl(sib, 15);
  const float taua = Tda + fabsf(Tda) * 1e-5f + 1e-12f;
  const float taub = Tdb + fabsf(Tdb) * 1e-5f + 1e-12f;

  // ---- pass B: collect stragglers ----
  for (int ch = 0; ch < 4; ++ch) {
    __syncthreads();
    for (int j = 0; j < 4; ++j) {
      int e = j * 512 + threadIdx.x;
      sp[e] = soa[ch * 2048 + e];
    }
    __syncthreads();
#pragma unroll 4
    for (int c = 0; c < 32; ++c) {
      const float4 P = sp[c * 64 + lane];
      const int gidx = ch * 2048 + c * 64 + lane;
      float da = fmaf(ax2, P.x, qa.w);
      da = fmaf(ay2, P.y, da);
      da = fmaf(az2, P.z, da);
      da += P.w;
      float db = fmaf(bx2, P.x, qb.w);
      db = fmaf(by2, P.y, db);
      db = fmaf(bz2, P.z, db);
      db += P.w;
      if (da <= taua && gidx != owna) {
        int slot = atomicAdd(&ccnt[wid * 2], 1);
        if (slot < KCAP) { cb_d[wid * 2][slot] = da; cb_i[wid * 2][slot] = gidx; }
      }
      if (db <= taub && gidx != ownb) {
        int slot = atomicAdd(&ccnt[wid * 2 + 1], 1);
        if (slot < KCAP) { cb_d[wid * 2 + 1][slot] = db; cb_i[wid * 2 + 1][slot] = gidx; }
      }
    }
  }

  // ---- drain query a ----
  int na = ccnt[wid * 2];
  if (na <= KCAP) {
    for (int k2 = 0; k2 < na; ++k2) {
      float cd = cb_d[wid * 2][k2];
      int ci = cb_i[wid * 2][k2];
      if (lexless(cd, ci, Tda, Tia)) {
        insert1(cd, ci, lane, tda, tia);
        Tda = __shfl(tda, 15); Tia = __shfl(tia, 15);
      }
    }
  } else {
    tda = INF; tia = 0x7fffffff; Tda = INF; Tia = 0x7fffffff;
    for (int base = 0; base < 8192; base += 64) {
      const float4 P = soa[base + lane];
      float d = fmaf(ax2, P.x, qa.w);
      d = fmaf(ay2, P.y, d);
      d = fmaf(az2, P.z, d);
      d += P.w;
      const int gidx = base + lane;
      u64 mk = __ballot(d <= taua && lexless(d, gidx, Tda, Tia));
      while (mk) {
        int s = (int)__builtin_ctzll(mk);
        mk &= mk - 1;
        float cd = __shfl(d, s);
        int ci = __shfl(gidx, s);
        insert1(cd, ci, lane, tda, tia);
      }
      Tda = __shfl(tda, 15); Tia = __shfl(tia, 15);
    }
  }
  // ---- drain query b ----
  int nb = ccnt[wid * 2 + 1];
  if (nb <= KCAP) {
    for (int k2 = 0; k2 < nb; ++k2) {
      float cd = cb_d[wid * 2 + 1][k2];
      int ci = cb_i[wid * 2 + 1][k2];
      if (lexless(cd, ci, Tdb, Tib)) {
        insert1(cd, ci, lane, tdb, tib);
        Tdb = __shfl(tdb, 15); Tib = __shfl(tib, 15);
      }
    }
  } else {
    tdb = INF; tib = 0x7fffffff; Tdb = INF; Tib = 0x7fffffff;
    for (int base = 0; base < 8192; base += 64) {
      const float4 P = soa[base + lane];
      float d = fmaf(bx2, P.x, qb.w);
      d = fmaf(by2, P.y, d);
      d = fmaf(bz2, P.z, d);
      d += P.w;
      const int gidx = base + lane;
      u64 mk = __ballot(d <= taub && lexless(d, gidx, Tdb, Tib));
      while (mk) {
        int s = (int)__builtin_ctzll(mk);
        mk &= mk - 1;
        float cd = __shfl(d, s);
        int ci = __shfl(gidx, s);
        insert1(cd, ci, lane, tdb, tib);
      }
      Tdb = __shfl(tdb, 15); Tib = __shfl(tib, 15);
    }
  }
  if (lane < 16) {
    idxout[q0 * 16 + lane] = tia & 8191;
    idxout[(q0 + 1) * 16 + lane] = tib & 8191;
  }
}

// ---------------- edge conv ----------------
__global__ __launch_bounds__(256) void proj1_k(const float4* __restrict__ soa,
                                               const float* __restrict__ We1,
                                               unsigned short* __restrict__ bz1) {
  int t = blockIdx.x * 256 + threadIdx.x;  // 8192*32
  int i = t >> 5, g = t & 31;
  float4 P = soa[i];
  us4 o;
#pragma unroll
  for (int j = 0; j < 4; ++j) {
    int c = 4 * g + j;
    float v;
    if (c < 64) {
      v = P.x * (We1[c] - We1[192 + c]) + P.y * (We1[64 + c] - We1[256 + c]) +
          P.z * (We1[128 + c] - We1[320 + c]);
    } else {
      int cc = c & 63;
      v = P.x * We1[192 + cc] + P.y * We1[256 + cc] + P.z * We1[320 + cc];
    }
    o[j] = f2h(v);
  }
  *(us4*)&bz1[(size_t)i * 128 + 4 * g] = o;
}

template <int C>
__global__ __launch_bounds__(256) void ec_gm_k(const unsigned short* __restrict__ bz,
                                               const int* __restrict__ idx,
                                               const float* __restrict__ s,
                                               const float* __restrict__ b,
                                               unsigned short* __restrict__ xo) {
  constexpr int C4 = C / 4;
  int t = blockIdx.x * 256 + threadIdx.x;  // NP*C4
  int i = t / C4, q = t % C4;
  us4 b4 = *(const us4*)&bz[(size_t)i * (2 * C) + q * 4];
  float bx = h2f(b4[0]), by = h2f(b4[1]), bz2v = h2f(b4[2]), bw = h2f(b4[3]);
  float4 scl = *(const float4*)&s[q * 4];
  float4 bia = *(const float4*)&b[q * 4];
  float ax = 0.f, ay = 0.f, az = 0.f, aw = 0.f;
  const int* ip = idx + i * 16;
#pragma unroll
  for (int n = 0; n < 16; ++n) {
    int j = ip[n];
    us4 z4 = *(const us4*)&bz[(size_t)j * (2 * C) + C + q * 4];
    ax = fmaxf(ax, (bx + h2f(z4[0])) * scl.x + bia.x);
    ay = fmaxf(ay, (by + h2f(z4[1])) * scl.y + bia.y);
    az = fmaxf(az, (bz2v + h2f(z4[2])) * scl.z + bia.z);
    aw = fmaxf(aw, (bw + h2f(z4[3])) * scl.w + bia.w);
  }
  us4 o;
  o[0] = f2h(ax); o[1] = f2h(ay); o[2] = f2h(az); o[3] = f2h(aw);
  *(us4*)&xo[(size_t)i * C + q * 4] = o;
}

// ---------------- fused attention (q fp16) ----------------
template <int C>
__global__ __launch_bounds__(256) void attn_fused_k(const unsigned short* __restrict__ qh,
                                                    const unsigned short* __restrict__ kvb,
                                                    const int* __restrict__ idx,
                                                    const float* __restrict__ s,
                                                    const float* __restrict__ b,
                                                    unsigned short* __restrict__ xo,
                                                    float scale) {
  int i = blockIdx.x * 4 + (threadIdx.x >> 6);
  int lane = threadIdx.x & 63;
  constexpr int G = C / 256;
  int jreg = (lane < 16) ? idx[i * 16 + lane] : 0;
  float qv[4 * G];
#pragma unroll
  for (int g = 0; g < G; ++g) {
    us4 qq = *(const us4*)&qh[(size_t)i * C + 4 * lane + 256 * g];
    qv[4 * g + 0] = h2f(qq[0]); qv[4 * g + 1] = h2f(qq[1]);
    qv[4 * g + 2] = h2f(qq[2]); qv[4 * g + 3] = h2f(qq[3]);
  }
  float lg[16];
#pragma unroll
  for (int n = 0; n < 16; ++n) {
    int j = __shfl(jreg, n);
    const unsigned short* kr = kvb + (size_t)j * (2 * C);
    float ssum = 0.f;
#pragma unroll
    for (int g = 0; g < G; ++g) {
      us4 kk = *(const us4*)&kr[4 * lane + 256 * g];
      ssum += qv[4 * g + 0] * h2f(kk[0]) + qv[4 * g + 1] * h2f(kk[1]) +
              qv[4 * g + 2] * h2f(kk[2]) + qv[4 * g + 3] * h2f(kk[3]);
    }
    lg[n] = ssum;
  }
#pragma unroll
  for (int n = 0; n < 16; ++n) {
    float vv = lg[n];
    for (int o = 32; o >= 1; o >>= 1) vv += __shfl_xor(vv, o);
    lg[n] = vv * scale;
  }
  float m = lg[0];
#pragma unroll
  for (int n = 1; n < 16; ++n) m = fmaxf(m, lg[n]);
  float ssum = 0.f;
#pragma unroll
  for (int n = 0; n < 16; ++n) { lg[n] = __expf(lg[n] - m); ssum += lg[n]; }
  float inv = 1.f / ssum;
#pragma unroll
  for (int n = 0; n < 16; ++n) lg[n] *= inv;

  float acc[4 * G];
#pragma unroll
  for (int e = 0; e < 4 * G; ++e) acc[e] = 0.f;
#pragma unroll
  for (int n = 0; n < 16; ++n) {
    int j = __shfl(jreg, n);
    const unsigned short* vr = kvb + (size_t)j * (2 * C) + C;
    float w = lg[n];
#pragma unroll
    for (int g = 0; g < G; ++g) {
      us4 v4 = *(const us4*)&vr[4 * lane + 256 * g];
      acc[4 * g + 0] += w * h2f(v4[0]);
      acc[4 * g + 1] += w * h2f(v4[1]);
      acc[4 * g + 2] += w * h2f(v4[2]);
      acc[4 * g + 3] += w * h2f(v4[3]);
    }
  }
#pragma unroll
  for (int g = 0; g < G; ++g) {
    int c0 = 4 * lane + 256 * g;
    float4 scl = *(const float4*)&s[c0];
    float4 bia = *(const float4*)&b[c0];
    us4 o;
    o[0] = f2h(fmaxf(acc[4 * g + 0] * scl.x + bia.x, 0.f));
    o[1] = f2h(fmaxf(acc[4 * g + 1] * scl.y + bia.y, 0.f));
    o[2] = f2h(fmaxf(acc[4 * g + 2] * scl.z + bia.z, 0.f));
    o[3] = f2h(fmaxf(acc[4 * g + 3] * scl.w + bia.w, 0.f));
    *(us4*)&xo[(size_t)i * C + c0] = o;
  }
}

// ---------------- down stage ----------------
__global__ __launch_bounds__(256) void down_gm_k(const unsigned short* __restrict__ vbuf,
                                                 const float4* __restrict__ soa,
                                                 const float* __restrict__ Wtd,
                                                 const int* __restrict__ idx,
                                                 const float* __restrict__ sd,
                                                 const float* __restrict__ bd,
                                                 unsigned short* __restrict__ xd) {
  int t = blockIdx.x * 256 + threadIdx.x;  // 2048*128
  int i = t >> 7, q = t & 127;
  int qi = 4 * i;
  float4 qp = soa[qi];
  float4 w0 = *(const float4*)&Wtd[q * 4];
  float4 w1 = *(const float4*)&Wtd[512 + q * 4];
  float4 w2 = *(const float4*)&Wtd[1024 + q * 4];
  float px = qp.x * w0.x + qp.y * w1.x + qp.z * w2.x;
  float py = qp.x * w0.y + qp.y * w1.y + qp.z * w2.y;
  float pz = qp.x * w0.z + qp.y * w1.z + qp.z * w2.z;
  float pw2 = qp.x * w0.w + qp.y * w1.w + qp.z * w2.w;
  float4 scl = *(const float4*)&sd[q * 4];
  float4 bia = *(const float4*)&bd[q * 4];
  float ax = 0.f, ay = 0.f, az = 0.f, aw = 0.f;
  const int* ip = idx + qi * 16;
#pragma unroll
  for (int n = 0; n < 16; ++n) {
    int j = ip[n];
    us4 v4 = *(const us4*)&vbuf[(size_t)j * 512 + q * 4];
    ax = fmaxf(ax, (h2f(v4[0]) - px) * scl.x + bia.x);
    ay = fmaxf(ay, (h2f(v4[1]) - py) * scl.y + bia.y);
    az = fmaxf(az, (h2f(v4[2]) - pz) * scl.z + bia.z);
    aw = fmaxf(aw, (h2f(v4[3]) - pw2) * scl.w + bia.w);
  }
  us4 o;
  o[0] = f2h(ax); o[1] = f2h(ay); o[2] = f2h(az); o[3] = f2h(aw);
  *(us4*)&xd[(size_t)i * 512 + q * 4] = o;
}

__global__ __launch_bounds__(512) void colsum_k(const unsigned short* __restrict__ xd,
                                                float* __restrict__ part) {
  int b = blockIdx.x;           // 16
  int c = threadIdx.x;          // 512
  float s = 0.f;
  for (int r = b * 128; r < (b + 1) * 128; ++r) s += h2f(xd[(size_t)r * 512 + c]);
  part[b * 512 + c] = s;
}

// 1 block x 256 thr; thread = output o; Wu2 reads coalesced (pre-r9 design).
__global__ __launch_bounds__(256) void gterm_k(const float* __restrict__ part,
                                               const float* __restrict__ Wu2,
                                               const float* __restrict__ su2,
                                               const float* __restrict__ bu2,
                                               float* __restrict__ gterm) {
  __shared__ float gm[512];
  int tid = threadIdx.x;
  for (int c = tid; c < 512; c += 256) {
    float s = 0.f;
#pragma unroll
    for (int b = 0; b < 16; ++b) s += part[b * 512 + c];
    gm[c] = s * (1.f / 2048.f);
  }
  __syncthreads();
  float s = 0.f;
  for (int c = 0; c < 512; ++c) s += gm[c] * Wu2[c * 256 + tid];
  gterm[tid] = s * su2[tid] + bu2[tid];
}

// ---------------- MFMA GEMM (fp16, 128x128 block, 64x64/wave) ----------------
// MODE 0: fp16 out. MODE 1: fp16 out += p@Wtd[0:3]. MODE 2: fp16
// relu(acc*s1+b1+s2). MODE 3: fp32 relu((acc+b1)*s1+s2). MODE 4: q fp16 +
// kv fp16 mixed (q cols < Cq -> Ch).
#define LDSROW 80
template <int MODE>
__global__ __launch_bounds__(256) void gemm_mfma(
    const unsigned short* __restrict__ A,
    const unsigned short* __restrict__ B,
    float* __restrict__ Cf, unsigned short* __restrict__ Ch,
    int M, int N, int K,
    const float4* __restrict__ soaD, const float* __restrict__ wtd,
    const float* __restrict__ s1, const float* __restrict__ b1,
    const float* __restrict__ s2, int Cq, unsigned short* __restrict__ kvb) {
  __shared__ __align__(16) char smem[2 * 128 * LDSROW];
  char* A_s = smem;
  char* B_s = smem + 128 * LDSROW;

  const int tid = threadIdx.x;
  const int lane = tid & 63;
  const int wid = tid >> 6;
  const int wm = wid >> 1, wn = wid & 1;
  const int bm = blockIdx.y * 128, bn = blockIdx.x * 128;
  const int r16 = lane & 15, kb = lane >> 4;

  f32x4 acc[4][4];
#pragma unroll
  for (int a = 0; a < 4; ++a)
#pragma unroll
    for (int b = 0; b < 4; ++b) acc[a][b] = (f32x4)(0.f);

  for (int k0 = 0; k0 < K; k0 += 32) {
    __syncthreads();
#pragma unroll
    for (int qq = 0; qq < 2; ++qq) {
      int idx8 = qq * 256 + tid;
      int row = idx8 >> 2, sq = idx8 & 3;
      size_t goA = (size_t)(bm + row) * K + k0 + sq * 8;
      size_t goB = (size_t)(bn + row) * K + k0 + sq * 8;
      ushort8 a_v = *(const ushort8*)&A[goA];
      ushort8 b_v = *(const ushort8*)&B[goB];
      *(ushort8*)(A_s + row * LDSROW + sq * 16) = a_v;
      *(ushort8*)(B_s + row * LDSROW + sq * 16) = b_v;
    }
    __syncthreads();

    half8 ah[4];
#pragma unroll
    for (int mi = 0; mi < 4; ++mi) {
      int off = (wm * 64 + mi * 16 + r16) * LDSROW + kb * 16;
      ah[mi] = *(const half8*)(A_s + off);
    }
#pragma unroll
    for (int ni = 0; ni < 4; ++ni) {
      int off = (wn * 64 + ni * 16 + r16) * LDSROW + kb * 16;
      half8 bh = *(const half8*)(B_s + off);
#pragma unroll
      for (int mi = 0; mi < 4; ++mi) {
        acc[mi][ni] = __builtin_amdgcn_mfma_f32_16x16x32_f16(ah[mi], bh, acc[mi][ni], 0, 0, 0);
      }
    }
  }

#pragma unroll
  for (int mi = 0; mi < 4; ++mi) {
#pragma unroll
    for (int ni = 0; ni < 4; ++ni) {
      int r0 = bm + wm * 64 + mi * 16 + (lane >> 4) * 4;
      int cc = bn + wn * 64 + ni * 16 + (lane & 15);
      float w0 = 0.f, w1 = 0.f, w2 = 0.f;
      if (MODE == 1) { w0 = wtd[cc]; w1 = wtd[512 + cc]; w2 = wtd[1024 + cc]; }
#pragma unroll
      for (int j = 0; j < 4; ++j) {
        float vv = acc[mi][ni][j];
        int row = r0 + j;
        if (MODE == 1) {
          float4 P = soaD[row];
          vv += P.x * w0 + P.y * w1 + P.z * w2;
        }
        if (MODE == 2) vv = fmaxf(vv * s1[cc] + b1[cc] + s2[cc], 0.f);
        if (MODE == 3) vv = fmaxf((vv + b1[cc]) * s1[cc] + s2[cc], 0.f);
        if (MODE == 0 || MODE == 1 || MODE == 2) {
          Ch[(size_t)row * N + cc] = f2h(vv);
        } else if (MODE == 4) {
          if (cc < Cq) Ch[(size_t)row * Cq + cc] = f2h(vv);
          else kvb[(size_t)row * (2 * Cq) + (cc - Cq)] = f2h(vv);
        } else {
          Cf[(size_t)row * N + cc] = vv;
        }
      }
    }
  }
}

// ---------------- final ----------------
__global__ __launch_bounds__(256) void out_k(const float* __restrict__ h,
                                             const float* __restrict__ Wc2,
                                             const float* __restrict__ bc2,
                                             float* __restrict__ out) {
  int t = blockIdx.x * 256 + threadIdx.x;  // 49152
  int pair = t >> 2, kq = t & 3;           // pair < 12288
  int i = pair / 6, o = pair % 6;
  float s = 0.f;
#pragma unroll 8
  for (int m = kq * 32; m < kq * 32 + 32; ++m) s += h[i * 128 + m] * Wc2[m * 6 + o];
  s += __shfl_xor(s, 1);
  s += __shfl_xor(s, 2);
  if (kq == 0) out[pair] = s + bc2[o];
}

extern "C" void kernel_launch(void* const* d_in, const int* in_sizes, int n_in,
                              void* d_out, int out_size, void* d_ws, size_t ws_size,
                              hipStream_t stream) {
  const float* pts = (const float*)d_in[0];
  const float* We1 = (const float*)d_in[1];
  const float* se1 = (const float*)d_in[2];
  const float* be1 = (const float*)d_in[3];
  const float* We2 = (const float*)d_in[4];
  const float* se2 = (const float*)d_in[5];
  const float* be2 = (const float*)d_in[6];
  const float* Wq1 = (const float*)d_in[7];
  const float* Wk1 = (const float*)d_in[8];
  const float* Wv1 = (const float*)d_in[9];
  const float* sa1 = (const float*)d_in[10];
  const float* ba1 = (const float*)d_in[11];
  const float* Wq2 = (const float*)d_in[12];
  const float* Wk2 = (const float*)d_in[13];
  const float* Wv2 = (const float*)d_in[14];
  const float* sa2 = (const float*)d_in[15];
  const float* ba2 = (const float*)d_in[16];
  const float* Wtd = (const float*)d_in[17];
  const float* sd  = (const float*)d_in[18];
  const float* bd  = (const float*)d_in[19];
  const float* Wu1 = (const float*)d_in[20];
  const float* su1 = (const float*)d_in[21];
  const float* bu1 = (const float*)d_in[22];
  const float* Wu2 = (const float*)d_in[23];
  const float* su2 = (const float*)d_in[24];
  const float* bu2 = (const float*)d_in[25];
  const float* Wc1 = (const float*)d_in[26];
  const float* bc1 = (const float*)d_in[27];
  const float* sc  = (const float*)d_in[28];
  const float* bc  = (const float*)d_in[29];
  const float* Wc2 = (const float*)d_in[30];
  const float* bc2 = (const float*)d_in[31];

  float* ws = (float*)d_ws;
  if (ws_size < (size_t)16703744 * 4) return;  // ~66.8 MB
  float* soa   = ws;                      // 32768
  int*   idx   = (int*)(ws + 32768);      // 131072 ints
  float* gpart = ws + 294912;             // 8192
  float* gterm = ws + 303104;             // 256
  unsigned short* wthi = (unsigned short*)(ws + 303360);   // 933888 ush
  unsigned short* x1   = (unsigned short*)(ws + 1237248);  // 524288 ush
  unsigned short* x2   = (unsigned short*)(ws + 1499392);  // 1048576 ush
  unsigned short* x3   = (unsigned short*)(ws + 2023680);  // 2097152 ush
  unsigned short* x4   = (unsigned short*)(ws + 3072256);  // 4194304 ush
  unsigned short* xd   = (unsigned short*)(ws + 5169408);  // 1048576 ush
  unsigned short* xu   = (unsigned short*)(ws + 5693696);  // 524288 ush
  unsigned short* bzb  = (unsigned short*)(ws + 5955840);  // bz fp16 (<=4 MB)
  float* qf    = ws + 8052992;            // 4194304 f (qh fp16 / vbuf fp16)
  unsigned short* qh   = (unsigned short*)qf;
  unsigned short* vbuf = (unsigned short*)qf;
  unsigned short* kvb = (unsigned short*)(ws + 12247296);  // 8388608 ush
  float* hbuf  = ws + 16441600;           // 262144 f

  prep_all_k<<<3680, 256, 0, stream>>>(pts, (float4*)soa, We2, Wq1, Wk1, Wv1,
                                       Wq2, Wk2, Wv2, Wtd, Wu1, Wc1, wthi);
  knn_k<<<512, 512, 0, stream>>>((const float4*)soa, idx);

  // edge conv 1: bz1 fp16; x1 fp16
  proj1_k<<<1024, 256, 0, stream>>>((const float4*)soa, We1, bzb);
  ec_gm_k<64><<<512, 256, 0, stream>>>(bzb, idx, se1, be1, x1);

  // edge conv 2: bz2 = x1 @ wcat2 (fp16, N=256); x2 fp16
  gemm_mfma<0><<<dim3(2, 64), 256, 0, stream>>>(x1, wthi,
      nullptr, bzb, NP, 256, 64, nullptr, nullptr, nullptr, nullptr, nullptr, 0, nullptr);
  ec_gm_k<128><<<1024, 256, 0, stream>>>(bzb, idx, se2, be2, x2);

  // attn 1: q fp16 + kv fp16 (N=768)
  gemm_mfma<4><<<dim3(6, 64), 256, 0, stream>>>(x2, wthi + 16384,
      nullptr, qh, NP, 768, 128, nullptr, nullptr, nullptr, nullptr, nullptr, 256, kvb);
  attn_fused_k<256><<<2048, 256, 0, stream>>>(qh, kvb, idx, sa1, ba1, x3, 0.0625f);

  // attn 2 (N=1536)
  gemm_mfma<4><<<dim3(12, 64), 256, 0, stream>>>(x3, wthi + 114688,
      nullptr, qh, NP, 1536, 256, nullptr, nullptr, nullptr, nullptr, nullptr, 512, kvb);
  attn_fused_k<512><<<2048, 256, 0, stream>>>(qh, kvb, idx, sa2, ba2, x4, 0.04419417382415922f);

  // down: vbuf = x4 @ wtdx + p@Wtd[0:3], fp16 (N=512)
  gemm_mfma<1><<<dim3(4, 64), 256, 0, stream>>>(x4, wthi + 507904,
      nullptr, vbuf, NP, 512, 512, (const float4*)soa, Wtd, nullptr, nullptr, nullptr, 0, nullptr);
  down_gm_k<<<1024, 256, 0, stream>>>(vbuf, (const float4*)soa, Wtd, idx, sd, bd, xd);

  // global mean term
  colsum_k<<<16, 512, 0, stream>>>(xd, gpart);
  gterm_k<<<1, 256, 0, stream>>>(gpart, Wu2, su2, bu2, gterm);

  // xu (N=256)
  gemm_mfma<2><<<dim3(2, 16), 256, 0, stream>>>(xd, wthi + 770048,
      nullptr, xu, NDOWN, 256, 512, nullptr, nullptr, su1, bu1, gterm, 0, nullptr);
  // h (N=128)
  gemm_mfma<3><<<dim3(1, 16), 256, 0, stream>>>(xu, wthi + 901120,
      hbuf, nullptr, NDOWN, 128, 256, nullptr, nullptr, sc, bc1, bc, 0, nullptr);
  // out
  out_k<<<192, 256, 0, stream>>>(hbuf, Wc2, bc2, (float*)d_out);
}

// Round 17
// 229.662 us; speedup vs baseline: 1.1601x; 1.0528x over previous
//
#include <hip/hip_runtime.h>

// DefectNet forward. Round 17 = round 14 (233.1us measured best) +
// gterm fixed structurally: Wu2 transposed once in prep (wu2t, fp32), gterm
// becomes wave-per-output with coalesced wu2t reads (64 blocks). r15/r16
// proved both prior gterm variants cost 25-70us (uncoalesced Wu2 stride-1KB
// or single-CU serialization).

#define NP 8192
#define NDOWN 2048
#define KCAP 32

typedef unsigned long long u64;
typedef __attribute__((ext_vector_type(8))) _Float16 half8;
typedef __attribute__((ext_vector_type(4))) unsigned short us4;
typedef __attribute__((ext_vector_type(8))) unsigned short ushort8;
typedef __attribute__((ext_vector_type(4))) float f32x4;

__device__ __forceinline__ bool lexless(float ad, int ai, float bd, int bi) {
  return ad < bd || (ad == bd && ai < bi);
}

__device__ __forceinline__ unsigned short f2h(float x) {
  _Float16 h = (_Float16)x;
  return __builtin_bit_cast(unsigned short, h);
}
__device__ __forceinline__ float h2f(unsigned short u) {
  return (float)__builtin_bit_cast(_Float16, u);
}

// ---------------- prep (points + weight transpose + Wu2^T, merged) ---------
__global__ __launch_bounds__(256) void prep_all_k(
    const float* __restrict__ pts, float4* __restrict__ soa,
    const float* __restrict__ We2, const float* __restrict__ Wq1,
    const float* __restrict__ Wk1, const float* __restrict__ Wv1,
    const float* __restrict__ Wq2, const float* __restrict__ Wk2,
    const float* __restrict__ Wv2, const float* __restrict__ Wtd,
    const float* __restrict__ Wu1, const float* __restrict__ Wc1,
    const float* __restrict__ Wu2, unsigned short* __restrict__ whi,
    float* __restrict__ wu2t) {
  int blk = blockIdx.x;
  if (blk < 32) {
    int i = blk * 256 + threadIdx.x;  // 8192
    float x = pts[3 * i], y = pts[3 * i + 1], z = pts[3 * i + 2];
    soa[i] = make_float4(x, y, z, x * x + y * y + z * z);
    return;
  }
  if (blk >= 3680) {
    int t2 = (blk - 3680) * 256 + threadIdx.x;  // 131072
    int o = t2 >> 9, c = t2 & 511;
    wu2t[t2] = Wu2[c * 256 + o];
    return;
  }
  int t = (blk - 32) * 256 + threadIdx.x;  // < 933888
  float v;
  if (t < 16384) {
    int n = t >> 6, k = t & 63;
    if (n < 128) v = We2[k * 128 + n] - We2[(k + 64) * 128 + n];
    else         v = We2[(k + 64) * 128 + (n - 128)];
  } else if (t < 114688) {
    int e = t - 16384;
    int n = e >> 7, k = e & 127;
    if (n < 256)      v = Wq1[k * 256 + n];
    else if (n < 512) v = Wk1[k * 256 + (n - 256)];
    else              v = Wv1[k * 256 + (n - 512)];
  } else if (t < 507904) {
    int e = t - 114688;
    int n = e >> 8, k = e & 255;
    if (n < 512)       v = Wq2[k * 512 + n];
    else if (n < 1024) v = Wk2[k * 512 + (n - 512)];
    else               v = Wv2[k * 512 + (n - 1024)];
  } else if (t < 770048) {
    int e = t - 507904;
    int n = e >> 9, k = e & 511;
    v = Wtd[(3 + k) * 512 + n];
  } else if (t < 901120) {
    int e = t - 770048;
    int n = e >> 9, k = e & 511;
    v = Wu1[k * 256 + n];
  } else {
    int e = t - 901120;
    int n = e >> 8, k = e & 255;
    v = Wc1[k * 128 + n];
  }
  whi[t] = f2h(v);
}

// ---------------- knn (frozen: 2 queries/wave, 512 blocks) ----------------
__device__ __forceinline__ void bitonic_lex64(float& d, int& i, int lane) {
#pragma unroll
  for (int k = 2; k <= 64; k <<= 1) {
#pragma unroll
    for (int j = k >> 1; j >= 1; j >>= 1) {
      float od = __shfl_xor(d, j);
      int oi = __shfl_xor(i, j);
      bool takeMin = (((lane & k) == 0) == ((lane & j) == 0));
      bool less = lexless(od, oi, d, i);
      if (takeMin == less) { d = od; i = oi; }
    }
  }
}

__device__ __forceinline__ void insert1(float cd, int ci, int lane,
                                        float& td, int& ti) {
  int p = __popcll(__ballot(lexless(td, ti, cd, ci)));
  if (p < 16) {
    float ud = __shfl_up(td, 1);
    int ui = __shfl_up(ti, 1);
    float ntd = td; int nti = ti;
    if (lane > p && lane < 16) { ntd = ud; nti = ui; }
    if (lane == p) { ntd = cd; nti = ci; }
    td = ntd; ti = nti;
  }
}

__global__ __launch_bounds__(512) void knn_k(const float4* __restrict__ soa,
                                             int* __restrict__ idxout) {
  __shared__ float4 sp[2048];
  __shared__ float cb_d[16][KCAP];
  __shared__ int cb_i[16][KCAP];
  __shared__ int ccnt[16];
  const int lane = threadIdx.x & 63;
  const int wid = threadIdx.x >> 6;
  const int q0 = blockIdx.x * 16 + wid * 2;
  const float4 qa = soa[q0];
  const float4 qb = soa[q0 + 1];
  const float ax2 = -2.f * qa.x, ay2 = -2.f * qa.y, az2 = -2.f * qa.z;
  const float bx2 = -2.f * qb.x, by2 = -2.f * qb.y, bz2 = -2.f * qb.z;
  const float INF = __int_as_float(0x7f800000);
  if (lane < 2) ccnt[wid * 2 + lane] = 0;

  // ---- pass A ----
  float mda = INF, mdb = INF;
  int mia = 0x7fffffff, mib = 0x7fffffff;
  for (int ch = 0; ch < 4; ++ch) {
    __syncthreads();
    for (int j = 0; j < 4; ++j) {
      int e = j * 512 + threadIdx.x;
      sp[e] = soa[ch * 2048 + e];
    }
    __syncthreads();
#pragma unroll 4
    for (int c = 0; c < 32; ++c) {
      const float4 P = sp[c * 64 + lane];
      const int gidx = ch * 2048 + c * 64 + lane;
      float da = fmaf(ax2, P.x, qa.w);
      da = fmaf(ay2, P.y, da);
      da = fmaf(az2, P.z, da);
      da += P.w;
      float db = fmaf(bx2, P.x, qb.w);
      db = fmaf(by2, P.y, db);
      db = fmaf(bz2, P.z, db);
      db += P.w;
      if (da < mda) { mda = da; mia = gidx; }
      if (db < mdb) { mdb = db; mib = gidx; }
    }
  }
  const int owna = mia;
  const int ownb = mib;
  float sda = mda; int sia = mia;
  float sdb = mdb; int sib = mib;
  bitonic_lex64(sda, sia, lane);
  bitonic_lex64(sdb, sib, lane);

  float tda = (lane < 16) ? sda : INF;
  int tia = (lane < 16) ? sia : 0x7fffffff;
  float tdb = (lane < 16) ? sdb : INF;
  int tib = (lane < 16) ? sib : 0x7fffffff;
  float Tda = __shfl(sda, 15); int Tia = __shfl(sia, 15);
  float Tdb = __shfl(sdb, 15); int Tib = __shfl(sib, 15);
  const float taua = Tda + fabsf(Tda) * 1e-5f + 1e-12f;
  const float taub = Tdb + fabsf(Tdb) * 1e-5f + 1e-12f;

  // ---- pass B: collect stragglers ----
  for (int ch = 0; ch < 4; ++ch) {
    __syncthreads();
    for (int j = 0; j < 4; ++j) {
      int e = j * 512 + threadIdx.x;
      sp[e] = soa[ch * 2048 + e];
    }
    __syncthreads();
#pragma unroll 4
    for (int c = 0; c < 32; ++c) {
      const float4 P = sp[c * 64 + lane];
      const int gidx = ch * 2048 + c * 64 + lane;
      float da = fmaf(ax2, P.x, qa.w);
      da = fmaf(ay2, P.y, da);
      da = fmaf(az2, P.z, da);
      da += P.w;
      float db = fmaf(bx2, P.x, qb.w);
      db = fmaf(by2, P.y, db);
      db = fmaf(bz2, P.z, db);
      db += P.w;
      if (da <= taua && gidx != owna) {
        int slot = atomicAdd(&ccnt[wid * 2], 1);
        if (slot < KCAP) { cb_d[wid * 2][slot] = da; cb_i[wid * 2][slot] = gidx; }
      }
      if (db <= taub && gidx != ownb) {
        int slot = atomicAdd(&ccnt[wid * 2 + 1], 1);
        if (slot < KCAP) { cb_d[wid * 2 + 1][slot] = db; cb_i[wid * 2 + 1][slot] = gidx; }
      }
    }
  }

  // ---- drain query a ----
  int na = ccnt[wid * 2];
  if (na <= KCAP) {
    for (int k2 = 0; k2 < na; ++k2) {
      float cd = cb_d[wid * 2][k2];
      int ci = cb_i[wid * 2][k2];
      if (lexless(cd, ci, Tda, Tia)) {
        insert1(cd, ci, lane, tda, tia);
        Tda = __shfl(tda, 15); Tia = __shfl(tia, 15);
      }
    }
  } else {
    tda = INF; tia = 0x7fffffff; Tda = INF; Tia = 0x7fffffff;
    for (int base = 0; base < 8192; base += 64) {
      const float4 P = soa[base + lane];
      float d = fmaf(ax2, P.x, qa.w);
      d = fmaf(ay2, P.y, d);
      d = fmaf(az2, P.z, d);
      d += P.w;
      const int gidx = base + lane;
      u64 mk = __ballot(d <= taua && lexless(d, gidx, Tda, Tia));
      while (mk) {
        int s = (int)__builtin_ctzll(mk);
        mk &= mk - 1;
        float cd = __shfl(d, s);
        int ci = __shfl(gidx, s);
        insert1(cd, ci, lane, tda, tia);
      }
      Tda = __shfl(tda, 15); Tia = __shfl(tia, 15);
    }
  }
  // ---- drain query b ----
  int nb = ccnt[wid * 2 + 1];
  if (nb <= KCAP) {
    for (int k2 = 0; k2 < nb; ++k2) {
      float cd = cb_d[wid * 2 + 1][k2];
      int ci = cb_i[wid * 2 + 1][k2];
      if (lexless(cd, ci, Tdb, Tib)) {
        insert1(cd, ci, lane, tdb, tib);
        Tdb = __shfl(tdb, 15); Tib = __shfl(tib, 15);
      }
    }
  } else {
    tdb = INF; tib = 0x7fffffff; Tdb = INF; Tib = 0x7fffffff;
    for (int base = 0; base < 8192; base += 64) {
      const float4 P = soa[base + lane];
      float d = fmaf(bx2, P.x, qb.w);
      d = fmaf(by2, P.y, d);
      d = fmaf(bz2, P.z, d);
      d += P.w;
      const int gidx = base + lane;
      u64 mk = __ballot(d <= taub && lexless(d, gidx, Tdb, Tib));
      while (mk) {
        int s = (int)__builtin_ctzll(mk);
        mk &= mk - 1;
        float cd = __shfl(d, s);
        int ci = __shfl(gidx, s);
        insert1(cd, ci, lane, tdb, tib);
      }
      Tdb = __shfl(tdb, 15); Tib = __shfl(tib, 15);
    }
  }
  if (lane < 16) {
    idxout[q0 * 16 + lane] = tia & 8191;
    idxout[(q0 + 1) * 16 + lane] = tib & 8191;
  }
}

// ---------------- edge conv ----------------
__global__ __launch_bounds__(256) void proj1_k(const float4* __restrict__ soa,
                                               const float* __restrict__ We1,
                                               unsigned short* __restrict__ bz1) {
  int t = blockIdx.x * 256 + threadIdx.x;  // 8192*32
  int i = t >> 5, g = t & 31;
  float4 P = soa[i];
  us4 o;
#pragma unroll
  for (int j = 0; j < 4; ++j) {
    int c = 4 * g + j;
    float v;
    if (c < 64) {
      v = P.x * (We1[c] - We1[192 + c]) + P.y * (We1[64 + c] - We1[256 + c]) +
          P.z * (We1[128 + c] - We1[320 + c]);
    } else {
      int cc = c & 63;
      v = P.x * We1[192 + cc] + P.y * We1[256 + cc] + P.z * We1[320 + cc];
    }
    o[j] = f2h(v);
  }
  *(us4*)&bz1[(size_t)i * 128 + 4 * g] = o;
}

template <int C>
__global__ __launch_bounds__(256) void ec_gm_k(const unsigned short* __restrict__ bz,
                                               const int* __restrict__ idx,
                                               const float* __restrict__ s,
                                               const float* __restrict__ b,
                                               unsigned short* __restrict__ xo) {
  constexpr int C4 = C / 4;
  int t = blockIdx.x * 256 + threadIdx.x;  // NP*C4
  int i = t / C4, q = t % C4;
  us4 b4 = *(const us4*)&bz[(size_t)i * (2 * C) + q * 4];
  float bx = h2f(b4[0]), by = h2f(b4[1]), bz2v = h2f(b4[2]), bw = h2f(b4[3]);
  float4 scl = *(const float4*)&s[q * 4];
  float4 bia = *(const float4*)&b[q * 4];
  float ax = 0.f, ay = 0.f, az = 0.f, aw = 0.f;
  const int* ip = idx + i * 16;
#pragma unroll
  for (int n = 0; n < 16; ++n) {
    int j = ip[n];
    us4 z4 = *(const us4*)&bz[(size_t)j * (2 * C) + C + q * 4];
    ax = fmaxf(ax, (bx + h2f(z4[0])) * scl.x + bia.x);
    ay = fmaxf(ay, (by + h2f(z4[1])) * scl.y + bia.y);
    az = fmaxf(az, (bz2v + h2f(z4[2])) * scl.z + bia.z);
    aw = fmaxf(aw, (bw + h2f(z4[3])) * scl.w + bia.w);
  }
  us4 o;
  o[0] = f2h(ax); o[1] = f2h(ay); o[2] = f2h(az); o[3] = f2h(aw);
  *(us4*)&xo[(size_t)i * C + q * 4] = o;
}

// ---------------- fused attention (q fp16) ----------------
template <int C>
__global__ __launch_bounds__(256) void attn_fused_k(const unsigned short* __restrict__ qh,
                                                    const unsigned short* __restrict__ kvb,
                                                    const int* __restrict__ idx,
                                                    const float* __restrict__ s,
                                                    const float* __restrict__ b,
                                                    unsigned short* __restrict__ xo,
                                                    float scale) {
  int i = blockIdx.x * 4 + (threadIdx.x >> 6);
  int lane = threadIdx.x & 63;
  constexpr int G = C / 256;
  int jreg = (lane < 16) ? idx[i * 16 + lane] : 0;
  float qv[4 * G];
#pragma unroll
  for (int g = 0; g < G; ++g) {
    us4 qq = *(const us4*)&qh[(size_t)i * C + 4 * lane + 256 * g];
    qv[4 * g + 0] = h2f(qq[0]); qv[4 * g + 1] = h2f(qq[1]);
    qv[4 * g + 2] = h2f(qq[2]); qv[4 * g + 3] = h2f(qq[3]);
  }
  float lg[16];
#pragma unroll
  for (int n = 0; n < 16; ++n) {
    int j = __shfl(jreg, n);
    const unsigned short* kr = kvb + (size_t)j * (2 * C);
    float ssum = 0.f;
#pragma unroll
    for (int g = 0; g < G; ++g) {
      us4 kk = *(const us4*)&kr[4 * lane + 256 * g];
      ssum += qv[4 * g + 0] * h2f(kk[0]) + qv[4 * g + 1] * h2f(kk[1]) +
              qv[4 * g + 2] * h2f(kk[2]) + qv[4 * g + 3] * h2f(kk[3]);
    }
    lg[n] = ssum;
  }
#pragma unroll
  for (int n = 0; n < 16; ++n) {
    float vv = lg[n];
    for (int o = 32; o >= 1; o >>= 1) vv += __shfl_xor(vv, o);
    lg[n] = vv * scale;
  }
  float m = lg[0];
#pragma unroll
  for (int n = 1; n < 16; ++n) m = fmaxf(m, lg[n]);
  float ssum = 0.f;
#pragma unroll
  for (int n = 0; n < 16; ++n) { lg[n] = __expf(lg[n] - m); ssum += lg[n]; }
  float inv = 1.f / ssum;
#pragma unroll
  for (int n = 0; n < 16; ++n) lg[n] *= inv;

  float acc[4 * G];
#pragma unroll
  for (int e = 0; e < 4 * G; ++e) acc[e] = 0.f;
#pragma unroll
  for (int n = 0; n < 16; ++n) {
    int j = __shfl(jreg, n);
    const unsigned short* vr = kvb + (size_t)j * (2 * C) + C;
    float w = lg[n];
#pragma unroll
    for (int g = 0; g < G; ++g) {
      us4 v4 = *(const us4*)&vr[4 * lane + 256 * g];
      acc[4 * g + 0] += w * h2f(v4[0]);
      acc[4 * g + 1] += w * h2f(v4[1]);
      acc[4 * g + 2] += w * h2f(v4[2]);
      acc[4 * g + 3] += w * h2f(v4[3]);
    }
  }
#pragma unroll
  for (int g = 0; g < G; ++g) {
    int c0 = 4 * lane + 256 * g;
    float4 scl = *(const float4*)&s[c0];
    float4 bia = *(const float4*)&b[c0];
    us4 o;
    o[0] = f2h(fmaxf(acc[4 * g + 0] * scl.x + bia.x, 0.f));
    o[1] = f2h(fmaxf(acc[4 * g + 1] * scl.y + bia.y, 0.f));
    o[2] = f2h(fmaxf(acc[4 * g + 2] * scl.z + bia.z, 0.f));
    o[3] = f2h(fmaxf(acc[4 * g + 3] * scl.w + bia.w, 0.f));
    *(us4*)&xo[(size_t)i * C + c0] = o;
  }
}

// ---------------- down stage ----------------
__global__ __launch_bounds__(256) void down_gm_k(const unsigned short* __restrict__ vbuf,
                                                 const float4* __restrict__ soa,
                                                 const float* __restrict__ Wtd,
                                                 const int* __restrict__ idx,
                                                 const float* __restrict__ sd,
                                                 const float* __restrict__ bd,
                                                 unsigned short* __restrict__ xd) {
  int t = blockIdx.x * 256 + threadIdx.x;  // 2048*128
  int i = t >> 7, q = t & 127;
  int qi = 4 * i;
  float4 qp = soa[qi];
  float4 w0 = *(const float4*)&Wtd[q * 4];
  float4 w1 = *(const float4*)&Wtd[512 + q * 4];
  float4 w2 = *(const float4*)&Wtd[1024 + q * 4];
  float px = qp.x * w0.x + qp.y * w1.x + qp.z * w2.x;
  float py = qp.x * w0.y + qp.y * w1.y + qp.z * w2.y;
  float pz = qp.x * w0.z + qp.y * w1.z + qp.z * w2.z;
  float pw2 = qp.x * w0.w + qp.y * w1.w + qp.z * w2.w;
  float4 scl = *(const float4*)&sd[q * 4];
  float4 bia = *(const float4*)&bd[q * 4];
  float ax = 0.f, ay = 0.f, az = 0.f, aw = 0.f;
  const int* ip = idx + qi * 16;
#pragma unroll
  for (int n = 0; n < 16; ++n) {
    int j = ip[n];
    us4 v4 = *(const us4*)&vbuf[(size_t)j * 512 + q * 4];
    ax = fmaxf(ax, (h2f(v4[0]) - px) * scl.x + bia.x);
    ay = fmaxf(ay, (h2f(v4[1]) - py) * scl.y + bia.y);
    az = fmaxf(az, (h2f(v4[2]) - pz) * scl.z + bia.z);
    aw = fmaxf(aw, (h2f(v4[3]) - pw2) * scl.w + bia.w);
  }
  us4 o;
  o[0] = f2h(ax); o[1] = f2h(ay); o[2] = f2h(az); o[3] = f2h(aw);
  *(us4*)&xd[(size_t)i * 512 + q * 4] = o;
}

__global__ __launch_bounds__(512) void colsum_k(const unsigned short* __restrict__ xd,
                                                float* __restrict__ part) {
  int b = blockIdx.x;           // 16
  int c = threadIdx.x;          // 512
  float s = 0.f;
  for (int r = b * 128; r < (b + 1) * 128; ++r) s += h2f(xd[(size_t)r * 512 + c]);
  part[b * 512 + c] = s;
}

// 64 blocks x 256 thr; one wave per output o; coalesced wu2t reads.
__global__ __launch_bounds__(256) void gterm_k(const float* __restrict__ part,
                                               const float* __restrict__ wu2t,
                                               const float* __restrict__ su2,
                                               const float* __restrict__ bu2,
                                               float* __restrict__ gterm) {
  int o = blockIdx.x * 4 + (threadIdx.x >> 6);
  int lane = threadIdx.x & 63;
  float dot = 0.f;
#pragma unroll
  for (int cb = 0; cb < 8; ++cb) {
    int c = cb * 64 + lane;
    float gm = 0.f;
#pragma unroll
    for (int b = 0; b < 16; ++b) gm += part[b * 512 + c];
    dot += gm * wu2t[o * 512 + c];
  }
  for (int off = 32; off >= 1; off >>= 1) dot += __shfl_xor(dot, off);
  if (lane == 0) gterm[o] = dot * (1.f / 2048.f) * su2[o] + bu2[o];
}

// ---------------- MFMA GEMM (fp16, 128x128 block, 64x64/wave) ----------------
// MODE 0: fp16 out. MODE 1: fp16 out += p@Wtd[0:3]. MODE 2: fp16
// relu(acc*s1+b1+s2). MODE 3: fp32 relu((acc+b1)*s1+s2). MODE 4: q fp16 +
// kv fp16 mixed (q cols < Cq -> Ch).
#define LDSROW 80
template <int MODE>
__global__ __launch_bounds__(256) void gemm_mfma(
    const unsigned short* __restrict__ A,
    const unsigned short* __restrict__ B,
    float* __restrict__ Cf, unsigned short* __restrict__ Ch,
    int M, int N, int K,
    const float4* __restrict__ soaD, const float* __restrict__ wtd,
    const float* __restrict__ s1, const float* __restrict__ b1,
    const float* __restrict__ s2, int Cq, unsigned short* __restrict__ kvb) {
  __shared__ __align__(16) char smem[2 * 128 * LDSROW];
  char* A_s = smem;
  char* B_s = smem + 128 * LDSROW;

  const int tid = threadIdx.x;
  const int lane = tid & 63;
  const int wid = tid >> 6;
  const int wm = wid >> 1, wn = wid & 1;
  const int bm = blockIdx.y * 128, bn = blockIdx.x * 128;
  const int r16 = lane & 15, kb = lane >> 4;

  f32x4 acc[4][4];
#pragma unroll
  for (int a = 0; a < 4; ++a)
#pragma unroll
    for (int b = 0; b < 4; ++b) acc[a][b] = (f32x4)(0.f);

  for (int k0 = 0; k0 < K; k0 += 32) {
    __syncthreads();
#pragma unroll
    for (int qq = 0; qq < 2; ++qq) {
      int idx8 = qq * 256 + tid;
      int row = idx8 >> 2, sq = idx8 & 3;
      size_t goA = (size_t)(bm + row) * K + k0 + sq * 8;
      size_t goB = (size_t)(bn + row) * K + k0 + sq * 8;
      ushort8 a_v = *(const ushort8*)&A[goA];
      ushort8 b_v = *(const ushort8*)&B[goB];
      *(ushort8*)(A_s + row * LDSROW + sq * 16) = a_v;
      *(ushort8*)(B_s + row * LDSROW + sq * 16) = b_v;
    }
    __syncthreads();

    half8 ah[4];
#pragma unroll
    for (int mi = 0; mi < 4; ++mi) {
      int off = (wm * 64 + mi * 16 + r16) * LDSROW + kb * 16;
      ah[mi] = *(const half8*)(A_s + off);
    }
#pragma unroll
    for (int ni = 0; ni < 4; ++ni) {
      int off = (wn * 64 + ni * 16 + r16) * LDSROW + kb * 16;
      half8 bh = *(const half8*)(B_s + off);
#pragma unroll
      for (int mi = 0; mi < 4; ++mi) {
        acc[mi][ni] = __builtin_amdgcn_mfma_f32_16x16x32_f16(ah[mi], bh, acc[mi][ni], 0, 0, 0);
      }
    }
  }

#pragma unroll
  for (int mi = 0; mi < 4; ++mi) {
#pragma unroll
    for (int ni = 0; ni < 4; ++ni) {
      int r0 = bm + wm * 64 + mi * 16 + (lane >> 4) * 4;
      int cc = bn + wn * 64 + ni * 16 + (lane & 15);
      float w0 = 0.f, w1 = 0.f, w2 = 0.f;
      if (MODE == 1) { w0 = wtd[cc]; w1 = wtd[512 + cc]; w2 = wtd[1024 + cc]; }
#pragma unroll
      for (int j = 0; j < 4; ++j) {
        float vv = acc[mi][ni][j];
        int row = r0 + j;
        if (MODE == 1) {
          float4 P = soaD[row];
          vv += P.x * w0 + P.y * w1 + P.z * w2;
        }
        if (MODE == 2) vv = fmaxf(vv * s1[cc] + b1[cc] + s2[cc], 0.f);
        if (MODE == 3) vv = fmaxf((vv + b1[cc]) * s1[cc] + s2[cc], 0.f);
        if (MODE == 0 || MODE == 1 || MODE == 2) {
          Ch[(size_t)row * N + cc] = f2h(vv);
        } else if (MODE == 4) {
          if (cc < Cq) Ch[(size_t)row * Cq + cc] = f2h(vv);
          else kvb[(size_t)row * (2 * Cq) + (cc - Cq)] = f2h(vv);
        } else {
          Cf[(size_t)row * N + cc] = vv;
        }
      }
    }
  }
}

// ---------------- final ----------------
__global__ __launch_bounds__(256) void out_k(const float* __restrict__ h,
                                             const float* __restrict__ Wc2,
                                             const float* __restrict__ bc2,
                                             float* __restrict__ out) {
  int t = blockIdx.x * 256 + threadIdx.x;  // 49152
  int pair = t >> 2, kq = t & 3;           // pair < 12288
  int i = pair / 6, o = pair % 6;
  float s = 0.f;
#pragma unroll 8
  for (int m = kq * 32; m < kq * 32 + 32; ++m) s += h[i * 128 + m] * Wc2[m * 6 + o];
  s += __shfl_xor(s, 1);
  s += __shfl_xor(s, 2);
  if (kq == 0) out[pair] = s + bc2[o];
}

extern "C" void kernel_launch(void* const* d_in, const int* in_sizes, int n_in,
                              void* d_out, int out_size, void* d_ws, size_t ws_size,
                              hipStream_t stream) {
  const float* pts = (const float*)d_in[0];
  const float* We1 = (const float*)d_in[1];
  const float* se1 = (const float*)d_in[2];
  const float* be1 = (const float*)d_in[3];
  const float* We2 = (const float*)d_in[4];
  const float* se2 = (const float*)d_in[5];
  const float* be2 = (const float*)d_in[6];
  const float* Wq1 = (const float*)d_in[7];
  const float* Wk1 = (const float*)d_in[8];
  const float* Wv1 = (const float*)d_in[9];
  const float* sa1 = (const float*)d_in[10];
  const float* ba1 = (const float*)d_in[11];
  const float* Wq2 = (const float*)d_in[12];
  const float* Wk2 = (const float*)d_in[13];
  const float* Wv2 = (const float*)d_in[14];
  const float* sa2 = (const float*)d_in[15];
  const float* ba2 = (const float*)d_in[16];
  const float* Wtd = (const float*)d_in[17];
  const float* sd  = (const float*)d_in[18];
  const float* bd  = (const float*)d_in[19];
  const float* Wu1 = (const float*)d_in[20];
  const float* su1 = (const float*)d_in[21];
  const float* bu1 = (const float*)d_in[22];
  const float* Wu2 = (const float*)d_in[23];
  const float* su2 = (const float*)d_in[24];
  const float* bu2 = (const float*)d_in[25];
  const float* Wc1 = (const float*)d_in[26];
  const float* bc1 = (const float*)d_in[27];
  const float* sc  = (const float*)d_in[28];
  const float* bc  = (const float*)d_in[29];
  const float* Wc2 = (const float*)d_in[30];
  const float* bc2 = (const float*)d_in[31];

  float* ws = (float*)d_ws;
  if (ws_size < (size_t)16834816 * 4) return;  // ~67.3 MB
  float* soa   = ws;                      // 32768
  int*   idx   = (int*)(ws + 32768);      // 131072 ints
  float* gpart = ws + 294912;             // 8192
  float* gterm = ws + 303104;             // 256
  unsigned short* wthi = (unsigned short*)(ws + 303360);   // 933888 ush
  unsigned short* x1   = (unsigned short*)(ws + 1237248);  // 524288 ush
  unsigned short* x2   = (unsigned short*)(ws + 1499392);  // 1048576 ush
  unsigned short* x3   = (unsigned short*)(ws + 2023680);  // 2097152 ush
  unsigned short* x4   = (unsigned short*)(ws + 3072256);  // 4194304 ush
  unsigned short* xd   = (unsigned short*)(ws + 5169408);  // 1048576 ush
  unsigned short* xu   = (unsigned short*)(ws + 5693696);  // 524288 ush
  unsigned short* bzb  = (unsigned short*)(ws + 5955840);  // bz fp16 (<=4 MB)
  float* qf    = ws + 8052992;            // 4194304 f (qh fp16 / vbuf fp16)
  unsigned short* qh   = (unsigned short*)qf;
  unsigned short* vbuf = (unsigned short*)qf;
  unsigned short* kvb = (unsigned short*)(ws + 12247296);  // 8388608 ush
  float* hbuf  = ws + 16441600;           // 262144 f
  float* wu2t  = ws + 16703744;           // 131072 f

  prep_all_k<<<4192, 256, 0, stream>>>(pts, (float4*)soa, We2, Wq1, Wk1, Wv1,
                                       Wq2, Wk2, Wv2, Wtd, Wu1, Wc1, Wu2, wthi, wu2t);
  knn_k<<<512, 512, 0, stream>>>((const float4*)soa, idx);

  // edge conv 1: bz1 fp16; x1 fp16
  proj1_k<<<1024, 256, 0, stream>>>((const float4*)soa, We1, bzb);
  ec_gm_k<64><<<512, 256, 0, stream>>>(bzb, idx, se1, be1, x1);

  // edge conv 2: bz2 = x1 @ wcat2 (fp16, N=256); x2 fp16
  gemm_mfma<0><<<dim3(2, 64), 256, 0, stream>>>(x1, wthi,
      nullptr, bzb, NP, 256, 64, nullptr, nullptr, nullptr, nullptr, nullptr, 0, nullptr);
  ec_gm_k<128><<<1024, 256, 0, stream>>>(bzb, idx, se2, be2, x2);

  // attn 1: q fp16 + kv fp16 (N=768)
  gemm_mfma<4><<<dim3(6, 64), 256, 0, stream>>>(x2, wthi + 16384,
      nullptr, qh, NP, 768, 128, nullptr, nullptr, nullptr, nullptr, nullptr, 256, kvb);
  attn_fused_k<256><<<2048, 256, 0, stream>>>(qh, kvb, idx, sa1, ba1, x3, 0.0625f);

  // attn 2 (N=1536)
  gemm_mfma<4><<<dim3(12, 64), 256, 0, stream>>>(x3, wthi + 114688,
      nullptr, qh, NP, 1536, 256, nullptr, nullptr, nullptr, nullptr, nullptr, 512, kvb);
  attn_fused_k<512><<<2048, 256, 0, stream>>>(qh, kvb, idx, sa2, ba2, x4, 0.04419417382415922f);

  // down: vbuf = x4 @ wtdx + p@Wtd[0:3], fp16 (N=512)
  gemm_mfma<1><<<dim3(4, 64), 256, 0, stream>>>(x4, wthi + 507904,
      nullptr, vbuf, NP, 512, 512, (const float4*)soa, Wtd, nullptr, nullptr, nullptr, 0, nullptr);
  down_gm_k<<<1024, 256, 0, stream>>>(vbuf, (const float4*)soa, Wtd, idx, sd, bd, xd);

  // global mean term
  colsum_k<<<16, 512, 0, stream>>>(xd, gpart);
  gterm_k<<<64, 256, 0, stream>>>(gpart, wu2t, su2, bu2, gterm);

  // xu (N=256)
  gemm_mfma<2><<<dim3(2, 16), 256, 0, stream>>>(xd, wthi + 770048,
      nullptr, xu, NDOWN, 256, 512, nullptr, nullptr, su1, bu1, gterm, 0, nullptr);
  // h (N=128)
  gemm_mfma<3><<<dim3(1, 16), 256, 0, stream>>>(xu, wthi + 901120,
      hbuf, nullptr, NDOWN, 128, 256, nullptr, nullptr, sc, bc1, bc, 0, nullptr);
  // out
  out_k<<<192, 256, 0, stream>>>(hbuf, Wc2, bc2, (float*)d_out);
}